// Round 8
// baseline (510.469 us; speedup 1.0000x reference)
//
#include <hip/hip_runtime.h>

#define NB 2
#define NC 6
#define NV 50000
#define ND 384
#define NF 64
#define NP 100000
#define NM 1369
#define NROW (NB*NV)   // 100000
#define TILE 32        // voxels per block; 100000 % 32 == 0 -> 3125 blocks

// Projection in fp32 matching numpy's einsum exactly: sequential
// left-to-right accumulation, NO fma contraction (numpy baseline loops
// do separate mul/add rounds). Returns valid flag + flat patch index.
__device__ inline void proj_one(const float* __restrict__ E,
                                const float* __restrict__ Km,
                                float x, float y, float z,
                                float Ws, float Hs, float sx, float sy,
                                bool& valid, int& flat)
{
#pragma clang fp contract(off)
    // cam_pts = E @ [x,y,z,1]  (j ascending, left-to-right)
    const float X = ((E[0]*x + E[1]*y) + E[2]*z) + E[3];
    const float Y = ((E[4]*x + E[5]*y) + E[6]*z) + E[7];
    const float Z = ((E[8]*x + E[9]*y) + E[10]*z) + E[11];
    // pix = K @ [X,Y,Z]
    const float p0 = (Km[0]*X + Km[1]*Y) + Km[2]*Z;
    const float p1 = (Km[3]*X + Km[4]*Y) + Km[5]*Z;
    const float p2 = (Km[6]*X + Km[7]*Y) + Km[8]*Z;
    const float den = fmaxf(p2, 1e-12f);
    const float u = p0 / den;
    const float v = p1 / den;
    valid = (Z > 0.0f) & (u >= 0.0f) & (u < Ws) & (v >= 0.0f) & (v < Hs);
    const float us = u * sx;          // coords * scale (fp32)
    const float vs = v * sy;
    int px = (int)(us / 14.0f);       // trunc toward zero == astype(int32)
    int py = (int)(vs / 14.0f);
    px = px < 0 ? 0 : (px > 36 ? 36 : px);
    py = py < 0 ? 0 : (py > 36 ? 36 : py);
    flat = py*37 + px;                // already within [0,1368]
}

// Fused: projection + gather-average + 3-layer MLP. One block = 32 voxels.
// LDS: sXT 448x36 f32 (64,512 B, 16B-aligned rows) + sB 4096 f32 (16,384 B)
// = 80,896 B -> 2 blocks/CU (2*80,896 = 161,792 <= 163,840).
__global__ __launch_bounds__(256) void fuse_mlp_kernel(
    const float* __restrict__ patch,   // (B,C,M,D)
    const float* __restrict__ vfeat,   // (B,V,F)
    const float* __restrict__ vcoord,  // (B,V,3)
    const float* __restrict__ imsz,    // (B,2)  [H,W]
    const float* __restrict__ intr,    // (B,C,3,3)
    const float* __restrict__ extr,    // (B,C,4,4)
    const float* __restrict__ W1, const float* __restrict__ b1,   // (448,256),(256)
    const float* __restrict__ W2, const float* __restrict__ b2,   // (256,64),(64)
    const float* __restrict__ W3, const float* __restrict__ b3,   // (64,16),(16)
    float* __restrict__ scores)        // ws: (B*V,16)
{
    __shared__ float sXT[448*36];   // X^T: [dim][voxel-in-tile], stride 36
    __shared__ float sB[4096];      // weight staging (union for W1/W2/W3 chunks)

    const int tid  = threadIdx.x;
    const int base = blockIdx.x * TILE;
    const int lane = tid & 63;
    const int wave = tid >> 6;

    // ---------------- Stage A: projection + gather-average ----------------
    for (int r = wave; r < TILE; r += 4) {
        const int n = base + r;
        const int b = n / NV;
        const float x = vcoord[(size_t)n*3+0];
        const float y = vcoord[(size_t)n*3+1];
        const float z = vcoord[(size_t)n*3+2];
        const float Hs = imsz[b*2+0];
        const float Ws = imsz[b*2+1];
        const float sx = 518.0f / fmaxf(Ws, 1e-6f);
        const float sy = 518.0f / fmaxf(Hs, 1e-6f);
        float acc[6] = {0.f,0.f,0.f,0.f,0.f,0.f};
        int cnt = 0;
        for (int c = 0; c < NC; ++c) {
            const float* E  = extr + (size_t)(b*NC + c)*16;
            const float* Km = intr + (size_t)(b*NC + c)*9;
            bool valid; int flat;
            proj_one(E, Km, x, y, z, Ws, Hs, sx, sy, valid, flat);
            if (valid) {
                const float* tp = patch + ((size_t)(b*NC + c)*NM + flat)*ND;
                #pragma unroll
                for (int j = 0; j < 6; ++j) acc[j] += tp[lane + 64*j];
                ++cnt;
            }
        }
        const float cf = fmaxf((float)cnt, 1.0f);
        #pragma unroll
        for (int j = 0; j < 6; ++j) sXT[(64 + lane + 64*j)*36 + r] = acc[j]/cf;
        sXT[lane*36 + r] = vfeat[(size_t)n*NF + lane];
    }
    __syncthreads();

    // ---------------- GEMM1: (32x448)@(448x256)+b1, relu ----------------
    const int tx = tid & 31;   // col group: cols tx*4..+3 and 128+tx*4..+3
    const int ty = tid >> 5;   // row group: rows ty*4..+3
    float acc1[4][8];
    #pragma unroll
    for (int i = 0; i < 4; ++i)
        #pragma unroll
        for (int j = 0; j < 8; ++j) acc1[i][j] = 0.f;

    for (int kc = 0; kc < 28; ++kc) {       // k chunks of 16
        #pragma unroll
        for (int i = 0; i < 4; ++i) {       // stage 16x256 of W1
            const int u4 = tid + 256*i;
            const int row = u4 >> 6;
            const int c4 = (u4 & 63) << 2;
            *(float4*)&sB[row*256 + c4] =
                *(const float4*)&W1[(size_t)(kc*16 + row)*256 + c4];
        }
        __syncthreads();
        #pragma unroll
        for (int k = 0; k < 16; ++k) {
            const float4 a4  = *(const float4*)&sXT[(kc*16 + k)*36 + ty*4];
            const float4 b40 = *(const float4*)&sB[k*256 + tx*4];
            const float4 b41 = *(const float4*)&sB[k*256 + 128 + tx*4];
            const float av[4] = {a4.x, a4.y, a4.z, a4.w};
            const float bv[8] = {b40.x,b40.y,b40.z,b40.w,b41.x,b41.y,b41.z,b41.w};
            #pragma unroll
            for (int i = 0; i < 4; ++i)
                #pragma unroll
                for (int j = 0; j < 8; ++j)
                    acc1[i][j] += av[i]*bv[j];
        }
        __syncthreads();
    }
    // write h1^T (relu) into sXT rows 0..255
    #pragma unroll
    for (int j = 0; j < 4; ++j) {
        const float bb0 = b1[tx*4 + j];
        const float bb1 = b1[128 + tx*4 + j];
        #pragma unroll
        for (int i = 0; i < 4; ++i) {
            sXT[(tx*4 + j)*36 + ty*4 + i]       = fmaxf(acc1[i][j]   + bb0, 0.f);
            sXT[(128 + tx*4 + j)*36 + ty*4 + i] = fmaxf(acc1[i][j+4] + bb1, 0.f);
        }
    }
    __syncthreads();

    // ---------------- GEMM2: (32x256)@(256x64)+b2, relu ----------------
    const int tx2 = tid & 15;  // cols tx2*4..+3
    const int ty2 = tid >> 4;  // rows ty2*2..+1
    float acc2[2][4];
    #pragma unroll
    for (int i = 0; i < 2; ++i)
        #pragma unroll
        for (int j = 0; j < 4; ++j) acc2[i][j] = 0.f;

    for (int kc = 0; kc < 4; ++kc) {        // k chunks of 64
        #pragma unroll
        for (int i = 0; i < 4; ++i) {       // stage 64x64 of W2
            const int u4 = tid + 256*i;
            const int row = u4 >> 4;
            const int c4 = (u4 & 15) << 2;
            *(float4*)&sB[row*64 + c4] =
                *(const float4*)&W2[(size_t)(kc*64 + row)*64 + c4];
        }
        __syncthreads();
        #pragma unroll 16
        for (int k = 0; k < 64; ++k) {
            const float2 a2 = *(const float2*)&sXT[(kc*64 + k)*36 + ty2*2];
            const float4 b4 = *(const float4*)&sB[k*64 + tx2*4];
            const float aa[2] = {a2.x, a2.y};
            const float bb[4] = {b4.x, b4.y, b4.z, b4.w};
            #pragma unroll
            for (int i = 0; i < 2; ++i)
                #pragma unroll
                for (int j = 0; j < 4; ++j)
                    acc2[i][j] += aa[i]*bb[j];
        }
        __syncthreads();
    }
    // write h2^T (relu) at sXT offset 256*36, and stage W3; one barrier
    float* sH2T = sXT + 256*36;
    #pragma unroll
    for (int j = 0; j < 4; ++j) {
        const float bb = b2[tx2*4 + j];
        #pragma unroll
        for (int i = 0; i < 2; ++i)
            sH2T[(tx2*4 + j)*36 + ty2*2 + i] = fmaxf(acc2[i][j] + bb, 0.f);
    }
    {   // stage full W3 (64x16) into sB
        const int row = tid >> 2;
        const int c4 = (tid & 3) << 2;
        *(float4*)&sB[row*16 + c4] = *(const float4*)&W3[(size_t)row*16 + c4];
    }
    __syncthreads();

    // ---------------- GEMM3: (32x64)@(64x16)+b3 ----------------
    const int row3 = tid >> 3;        // 0..31
    const int cp   = (tid & 7) << 1;  // col pair
    float s0 = b3[cp], s1 = b3[cp+1];
    #pragma unroll 16
    for (int k = 0; k < 64; ++k) {
        const float a  = sH2T[k*36 + row3];
        const float2 w = *(const float2*)&sB[k*16 + cp];
        s0 += a*w.x;
        s1 += a*w.y;
    }
    const int n3 = base + row3;
    *(float2*)&scores[(size_t)n3*16 + cp] = make_float2(s0, s1);
}

// out[b,p,:] = scores[b*V + idx[b,p], :]; one thread = one float4 (4 of 16 cols)
__global__ __launch_bounds__(256) void gather_kernel(
    const float* __restrict__ scores,
    const int* __restrict__ p2v,
    float* __restrict__ out)
{
    const int g  = blockIdx.x * 256 + threadIdx.x;  // < B*P*4 = 800000
    const int q  = g & 3;
    const int pl = g >> 2;          // = b*NP + p  (0..199999)
    const int b  = pl / NP;
    const int idx = p2v[pl];
    const float4 val = *(const float4*)&scores[((size_t)(b*NV + idx))*16 + q*4];
    *(float4*)&out[(size_t)g*4] = val;
}

extern "C" void kernel_launch(void* const* d_in, const int* in_sizes, int n_in,
                              void* d_out, int out_size, void* d_ws, size_t ws_size,
                              hipStream_t stream) {
    const float* patch = (const float*)d_in[0];
    const float* vfeat = (const float*)d_in[1];
    const float* vcoord= (const float*)d_in[2];
    const float* imsz  = (const float*)d_in[3];
    const float* intr  = (const float*)d_in[4];
    const float* extr  = (const float*)d_in[5];
    const int*   p2v   = (const int*)d_in[6];
    const float* W1 = (const float*)d_in[7];
    const float* b1 = (const float*)d_in[8];
    const float* W2 = (const float*)d_in[9];
    const float* b2 = (const float*)d_in[10];
    const float* W3 = (const float*)d_in[11];
    const float* b3 = (const float*)d_in[12];

    float* scores = (float*)d_ws;   // B*V*16 f32 = 6.4 MB

    fuse_mlp_kernel<<<NROW/TILE, 256, 0, stream>>>(
        patch, vfeat, vcoord, imsz, intr, extr,
        W1, b1, W2, b2, W3, b3, scores);
    gather_kernel<<<(NB*NP*4)/256, 256, 0, stream>>>(scores, p2v, (float*)d_out);
}

// Round 9
// 213.455 us; speedup vs baseline: 2.3915x; 2.3915x over previous
//
#include <hip/hip_runtime.h>

#define NB 2
#define NC 6
#define NV 50000
#define ND 384
#define NF 64
#define NP 100000
#define NM 1369
#define NROW (NB*NV)   // 100000
#define TILE 32        // voxels per block -> 3125 blocks

typedef __attribute__((ext_vector_type(8))) short bf8_t;   // 8 bf16 (4 VGPRs)
typedef __attribute__((ext_vector_type(4))) float f4_t;    // 4 fp32 acc

// RNE float->bf16 (no NaN handling needed; inputs finite)
__device__ inline unsigned short f2bf(float x) {
    unsigned u = __builtin_bit_cast(unsigned, x);
    u += 0x7fffu + ((u >> 16) & 1u);
    return (unsigned short)(u >> 16);
}

// fp32 projection matching numpy einsum exactly (verified round 8: absmax 1.2e-4)
__device__ inline void proj_one(const float* __restrict__ E,
                                const float* __restrict__ Km,
                                float x, float y, float z,
                                float Ws, float Hs, float sx, float sy,
                                bool& valid, int& flat)
{
#pragma clang fp contract(off)
    const float X = ((E[0]*x + E[1]*y) + E[2]*z) + E[3];
    const float Y = ((E[4]*x + E[5]*y) + E[6]*z) + E[7];
    const float Z = ((E[8]*x + E[9]*y) + E[10]*z) + E[11];
    const float p0 = (Km[0]*X + Km[1]*Y) + Km[2]*Z;
    const float p1 = (Km[3]*X + Km[4]*Y) + Km[5]*Z;
    const float p2 = (Km[6]*X + Km[7]*Y) + Km[8]*Z;
    const float den = fmaxf(p2, 1e-12f);
    const float u = p0 / den;
    const float v = p1 / den;
    valid = (Z > 0.0f) & (u >= 0.0f) & (u < Ws) & (v >= 0.0f) & (v < Hs);
    const float us = u * sx;
    const float vs = v * sy;
    int px = (int)(us / 14.0f);
    int py = (int)(vs / 14.0f);
    px = px < 0 ? 0 : (px > 36 ? 36 : px);
    py = py < 0 ? 0 : (py > 36 ? 36 : py);
    flat = py*37 + px;
}

// Prepack W1 (448x256 f32) -> fragment-ordered bf16.
// Lane l of wave w, frag (kc,nf) reads 16B = 8 bf16: W1[kc*32+(l>>4)*8+i][w*64+nf*16+(l&15)]
// stored at ushort idx ((kc*16+w*4+nf)*64 + l)*8 + i  -> per-instr 64 lanes cover 1KB contig.
__global__ __launch_bounds__(256) void pack_w1(const float* __restrict__ W1,
                                               unsigned short* __restrict__ out) {
    const int t = blockIdx.x*256 + threadIdx.x;      // < 448*256
    const int k = t >> 8, n = t & 255;
    const int kc = k >> 5, g = (k >> 3) & 3, i = k & 7;
    const int w = n >> 6, nf = (n >> 4) & 3, m = n & 15;
    out[(((kc*16 + w*4 + nf)*64 + g*16 + m) << 3) + i] = f2bf(W1[k*256 + n]);
}

// Prepack W2 (256x64): frag (kc,nf): W2[kc*32+(l>>4)*8+i][nf*16+(l&15)]
__global__ __launch_bounds__(256) void pack_w2(const float* __restrict__ W2,
                                               unsigned short* __restrict__ out) {
    const int t = blockIdx.x*256 + threadIdx.x;      // < 256*64
    const int k = t >> 6, n = t & 63;
    const int kc = k >> 5, g = (k >> 3) & 3, i = k & 7;
    const int nf = n >> 4, m = n & 15;
    out[(((kc*4 + nf)*64 + g*16 + m) << 3) + i] = f2bf(W2[k*64 + n]);
}

// Fused: projection + gather-average (fp32 exact) + MFMA MLP.
// LDS: sX bf16 [32][456] (29,184B) + sH1 bf16 [32][264] (16,896B) = 46,080B -> 3 blocks/CU.
// sH2/sW3/sB3 overlay sX (dead after GEMM1). 3 barriers total.
__global__ __launch_bounds__(256) void fuse_mlp_kernel(
    const float* __restrict__ patch,   // (B,C,M,D)
    const float* __restrict__ vfeat,   // (B,V,F)
    const float* __restrict__ vcoord,  // (B,V,3)
    const float* __restrict__ imsz,    // (B,2)
    const float* __restrict__ intr,    // (B,C,3,3)
    const float* __restrict__ extr,    // (B,C,4,4)
    const float* __restrict__ b1,
    const float* __restrict__ b2,
    const float* __restrict__ W3, const float* __restrict__ b3,
    const unsigned short* __restrict__ w1p_,  // packed bf16 W1
    const unsigned short* __restrict__ w2p_,  // packed bf16 W2
    float* __restrict__ scores)        // ws: (B*V,16)
{
    __shared__ __align__(16) unsigned short sX[TILE*456];   // X bf16 [m][k], pad->228 dwords stride (%32==4)
    __shared__ __align__(16) unsigned short sH1[TILE*264];  // h1 bf16 [m][k2], 132-dword stride
    float* sH2 = (float*)sX;                 // [64][36] f32 (9,216B)
    float* sW3 = (float*)&sX[4608];          // byte 9216: [64][16] f32 (4,096B)
    float* sB3 = (float*)&sX[4608 + 2048];   // byte 13312: [16] f32

    const int tid  = threadIdx.x;
    const int base = blockIdx.x * TILE;
    const int lane = tid & 63;
    const int w    = tid >> 6;         // wave 0..3
    const int mrow = lane & 15;
    const int kg   = lane >> 4;

    // ---------- Stage A: projection + gather-average -> sX bf16 ----------
    for (int r = w; r < TILE; r += 4) {
        const int n = base + r;
        const int b = n / NV;
        const float x = vcoord[(size_t)n*3+0];
        const float y = vcoord[(size_t)n*3+1];
        const float z = vcoord[(size_t)n*3+2];
        const float Hs = imsz[b*2+0];
        const float Ws = imsz[b*2+1];
        const float sx = 518.0f / fmaxf(Ws, 1e-6f);
        const float sy = 518.0f / fmaxf(Hs, 1e-6f);
        float acc[6] = {0.f,0.f,0.f,0.f,0.f,0.f};
        int cnt = 0;
        for (int c = 0; c < NC; ++c) {
            const float* E  = extr + (size_t)(b*NC + c)*16;
            const float* Km = intr + (size_t)(b*NC + c)*9;
            bool valid; int flat;
            proj_one(E, Km, x, y, z, Ws, Hs, sx, sy, valid, flat);
            if (valid) {
                const float* tp = patch + ((size_t)(b*NC + c)*NM + flat)*ND;
                #pragma unroll
                for (int j = 0; j < 6; ++j) acc[j] += tp[lane + 64*j];
                ++cnt;
            }
        }
        const float cf = fmaxf((float)cnt, 1.0f);
        #pragma unroll
        for (int j = 0; j < 6; ++j)
            sX[r*456 + 64 + j*64 + lane] = f2bf(acc[j]/cf);
        sX[r*456 + lane] = f2bf(vfeat[(size_t)n*NF + lane]);
    }
    __syncthreads();

    // ---------- GEMM1 (MFMA): h1 = relu(X(32x448) @ W1(448x256) + b1) ----------
    // wave w owns cols w*64..w*64+63: 2 m-frags x 4 n-frags, K = 14 steps of 32
    const bf8_t* w1p = (const bf8_t*)w1p_;
    const f4_t zero = {0.f, 0.f, 0.f, 0.f};
    f4_t acc1[2][4];
    #pragma unroll
    for (int a = 0; a < 2; ++a)
        #pragma unroll
        for (int q = 0; q < 4; ++q) acc1[a][q] = zero;

    for (int kc = 0; kc < 14; ++kc) {
        const bf8_t a0 = *(const bf8_t*)&sX[ mrow      *456 + kc*32 + kg*8];
        const bf8_t a1 = *(const bf8_t*)&sX[(mrow + 16)*456 + kc*32 + kg*8];
        const bf8_t* bp = w1p + (size_t)((kc*16 + w*4)*64 + lane);
        #pragma unroll
        for (int nf = 0; nf < 4; ++nf) {
            const bf8_t bfr = bp[nf*64];
            acc1[0][nf] = __builtin_amdgcn_mfma_f32_16x16x32_bf16(a0, bfr, acc1[0][nf], 0, 0, 0);
            acc1[1][nf] = __builtin_amdgcn_mfma_f32_16x16x32_bf16(a1, bfr, acc1[1][nf], 0, 0, 0);
        }
    }
    // C/D: col = lane&15 (within nf), row = kg*4 + reg (+16*mf). bias+relu -> sH1 bf16 [m][k2]
    #pragma unroll
    for (int nf = 0; nf < 4; ++nf) {
        const float bb = b1[w*64 + nf*16 + mrow];
        #pragma unroll
        for (int mf = 0; mf < 2; ++mf)
            #pragma unroll
            for (int r = 0; r < 4; ++r) {
                const float v = fmaxf(acc1[mf][nf][r] + bb, 0.f);
                sH1[(mf*16 + kg*4 + r)*264 + w*64 + nf*16 + mrow] = f2bf(v);
            }
    }
    __syncthreads();

    // stage W3 + b3 into overlay region (sX dead)
    *(f4_t*)&sW3[tid*4] = *(const f4_t*)&W3[tid*4];
    if (tid < 16) sB3[tid] = b3[tid];

    // ---------- GEMM2 (MFMA): h2 = relu(h1(32x256) @ W2(256x64) + b2) ----------
    // wave w owns cols w*16..w*16+15 (nf = w), K = 8 steps of 32; no reduction needed
    const bf8_t* w2p = (const bf8_t*)w2p_;
    f4_t acc2[2];
    acc2[0] = zero; acc2[1] = zero;
    for (int kc = 0; kc < 8; ++kc) {
        const bf8_t a0 = *(const bf8_t*)&sH1[ mrow      *264 + kc*32 + kg*8];
        const bf8_t a1 = *(const bf8_t*)&sH1[(mrow + 16)*264 + kc*32 + kg*8];
        const bf8_t bfr = w2p[(kc*4 + w)*64 + lane];
        acc2[0] = __builtin_amdgcn_mfma_f32_16x16x32_bf16(a0, bfr, acc2[0], 0, 0, 0);
        acc2[1] = __builtin_amdgcn_mfma_f32_16x16x32_bf16(a1, bfr, acc2[1], 0, 0, 0);
    }
    {   // write h2 f32 [n2][m] (pad 36): col n2 = w*16+mrow, rows kg*4..+3 (+16*mf) -> one b128/frag
        const float bb = b2[w*16 + mrow];
        #pragma unroll
        for (int mf = 0; mf < 2; ++mf) {
            f4_t v;
            #pragma unroll
            for (int r = 0; r < 4; ++r) v[r] = fmaxf(acc2[mf][r] + bb, 0.f);
            *(f4_t*)&sH2[(w*16 + mrow)*36 + mf*16 + kg*4] = v;
        }
    }
    __syncthreads();

    // ---------- GEMM3 (VALU fp32): scores = h2(32x64) @ W3(64x16) + b3 ----------
    const int m3 = tid >> 3;            // voxel 0..31
    const int cp = (tid & 7) << 1;      // col pair
    float s0 = sB3[cp], s1 = sB3[cp+1];
    #pragma unroll 8
    for (int k = 0; k < 64; ++k) {
        const float a  = sH2[k*36 + m3];
        const float2 wv = *(const float2*)&sW3[k*16 + cp];
        s0 += a*wv.x;
        s1 += a*wv.y;
    }
    *(float2*)&scores[(size_t)(base + m3)*16 + cp] = make_float2(s0, s1);
}

// out[b,p,:] = scores[b*V + idx[b,p], :]
__global__ __launch_bounds__(256) void gather_kernel(
    const float* __restrict__ scores,
    const int* __restrict__ p2v,
    float* __restrict__ out)
{
    const int g  = blockIdx.x * 256 + threadIdx.x;  // < 800000
    const int q  = g & 3;
    const int pl = g >> 2;
    const int b  = pl / NP;
    const int idx = p2v[pl];
    const float4 val = *(const float4*)&scores[((size_t)(b*NV + idx))*16 + q*4];
    *(float4*)&out[(size_t)g*4] = val;
}

extern "C" void kernel_launch(void* const* d_in, const int* in_sizes, int n_in,
                              void* d_out, int out_size, void* d_ws, size_t ws_size,
                              hipStream_t stream) {
    const float* patch = (const float*)d_in[0];
    const float* vfeat = (const float*)d_in[1];
    const float* vcoord= (const float*)d_in[2];
    const float* imsz  = (const float*)d_in[3];
    const float* intr  = (const float*)d_in[4];
    const float* extr  = (const float*)d_in[5];
    const int*   p2v   = (const int*)d_in[6];
    const float* W1 = (const float*)d_in[7];
    const float* b1 = (const float*)d_in[8];
    const float* W2 = (const float*)d_in[9];
    const float* b2 = (const float*)d_in[10];
    const float* W3 = (const float*)d_in[11];
    const float* b3 = (const float*)d_in[12];

    float* scores = (float*)d_ws;                                       // 6,400,000 B
    unsigned short* w1pack = (unsigned short*)((char*)d_ws + 6400000);  // 229,376 B
    unsigned short* w2pack = (unsigned short*)((char*)d_ws + 6400000 + 229376); // 32,768 B

    pack_w1<<<448, 256, 0, stream>>>(W1, w1pack);
    pack_w2<<<64, 256, 0, stream>>>(W2, w2pack);
    fuse_mlp_kernel<<<NROW/TILE, 256, 0, stream>>>(
        patch, vfeat, vcoord, imsz, intr, extr,
        b1, b2, W3, b3, w1pack, w2pack, scores);
    gather_kernel<<<(NB*NP*4)/256, 256, 0, stream>>>(scores, p2v, (float*)d_out);
}

// Round 10
// 117.061 us; speedup vs baseline: 4.3607x; 1.8234x over previous
//
#include <hip/hip_runtime.h>

#define NB 2
#define NC 6
#define NV 50000
#define ND 384
#define NF 64
#define NP 100000
#define NM 1369
#define NROW (NB*NV)   // 100000
#define TILE 32        // voxels per block -> 3125 blocks

typedef __attribute__((ext_vector_type(8))) short bf8_t;   // 8 bf16 (4 VGPRs)
typedef __attribute__((ext_vector_type(4))) float f4_t;    // 4 fp32 acc

// RNE float->bf16 (inputs finite)
__device__ inline unsigned short f2bf(float x) {
    unsigned u = __builtin_bit_cast(unsigned, x);
    u += 0x7fffu + ((u >> 16) & 1u);
    return (unsigned short)(u >> 16);
}
__device__ inline unsigned pack2bf(float lo, float hi) {
    return (unsigned)f2bf(lo) | ((unsigned)f2bf(hi) << 16);
}

// fp32 projection matching numpy einsum exactly (verified r8/r9: passes)
__device__ inline void proj_one(const float* __restrict__ E,
                                const float* __restrict__ Km,
                                float x, float y, float z,
                                float Ws, float Hs, float sx, float sy,
                                bool& valid, int& flat)
{
#pragma clang fp contract(off)
    const float X = ((E[0]*x + E[1]*y) + E[2]*z) + E[3];
    const float Y = ((E[4]*x + E[5]*y) + E[6]*z) + E[7];
    const float Z = ((E[8]*x + E[9]*y) + E[10]*z) + E[11];
    const float p0 = (Km[0]*X + Km[1]*Y) + Km[2]*Z;
    const float p1 = (Km[3]*X + Km[4]*Y) + Km[5]*Z;
    const float p2 = (Km[6]*X + Km[7]*Y) + Km[8]*Z;
    const float den = fmaxf(p2, 1e-12f);
    const float u = p0 / den;
    const float v = p1 / den;
    valid = (Z > 0.0f) & (u >= 0.0f) & (u < Ws) & (v >= 0.0f) & (v < Hs);
    const float us = u * sx;
    const float vs = v * sy;
    int px = (int)(us / 14.0f);
    int py = (int)(vs / 14.0f);
    px = px < 0 ? 0 : (px > 36 ? 36 : px);
    py = py < 0 ? 0 : (py > 36 ? 36 : py);
    flat = py*37 + px;
}

// Prepack W1 (448x256 f32) -> fragment-ordered bf16 (1KB contig per wave-frag).
__global__ __launch_bounds__(256) void pack_w1(const float* __restrict__ W1,
                                               unsigned short* __restrict__ out) {
    const int t = blockIdx.x*256 + threadIdx.x;      // < 448*256
    const int k = t >> 8, n = t & 255;
    const int kc = k >> 5, g = (k >> 3) & 3, i = k & 7;
    const int w = n >> 6, nf = (n >> 4) & 3, m = n & 15;
    out[(((kc*16 + w*4 + nf)*64 + g*16 + m) << 3) + i] = f2bf(W1[k*256 + n]);
}

// Prepack W2 (256x64)
__global__ __launch_bounds__(256) void pack_w2(const float* __restrict__ W2,
                                               unsigned short* __restrict__ out) {
    const int t = blockIdx.x*256 + threadIdx.x;      // < 256*64
    const int k = t >> 6, n = t & 63;
    const int kc = k >> 5, g = (k >> 3) & 3, i = k & 7;
    const int nf = n >> 4, m = n & 15;
    out[(((kc*4 + nf)*64 + g*16 + m) << 3) + i] = f2bf(W2[k*64 + n]);
}

// Fused: A1 pair-parallel projection -> A2 gather-average -> MFMA MLP.
// LDS: sX 29,184B + sH1 16,896B + sFlat 768B = 46,848B -> 3 blocks/CU.
__global__ __launch_bounds__(256) void fuse_mlp_kernel(
    const float* __restrict__ patch,   // (B,C,M,D)
    const float* __restrict__ vfeat,   // (B,V,F)
    const float* __restrict__ vcoord,  // (B,V,3)
    const float* __restrict__ imsz,    // (B,2)
    const float* __restrict__ intr,    // (B,C,3,3)
    const float* __restrict__ extr,    // (B,C,4,4)
    const float* __restrict__ b1,
    const float* __restrict__ b2,
    const float* __restrict__ W3, const float* __restrict__ b3,
    const unsigned short* __restrict__ w1p_,  // packed bf16 W1
    const unsigned short* __restrict__ w2p_,  // packed bf16 W2
    float* __restrict__ scores)        // ws: (B*V,16)
{
    __shared__ __align__(16) unsigned short sX[TILE*456];   // X bf16 [m][k], u32-stride 228 (%32==4)
    __shared__ __align__(16) unsigned short sH1[TILE*264];  // h1 bf16 [m][k2]
    __shared__ int sFlat[NC*TILE];                          // [cam][voxel]: flat or -1
    float* sH2 = (float*)sX;                 // overlay: [64][36] f32
    float* sW3 = (float*)&sX[4608];          // overlay: [64][16] f32
    float* sB3 = (float*)&sX[4608 + 2048];   // overlay: [16] f32

    const int tid  = threadIdx.x;
    const int base = blockIdx.x * TILE;
    const int lane = tid & 63;
    const int w    = tid >> 6;         // wave 0..3
    const int mrow = lane & 15;
    const int kg   = lane >> 4;

    // ---------- A1: pair-parallel projection (one thread = one voxel-cam) ----------
    if (tid < NC*TILE) {
        const int r = tid & 31, c = tid >> 5;
        const int n = base + r;
        const int b = n / NV;
        const float x = vcoord[(size_t)n*3+0];
        const float y = vcoord[(size_t)n*3+1];
        const float z = vcoord[(size_t)n*3+2];
        const float Hs = imsz[b*2+0];
        const float Ws = imsz[b*2+1];
        const float sx = 518.0f / fmaxf(Ws, 1e-6f);
        const float sy = 518.0f / fmaxf(Hs, 1e-6f);
        const float* E  = extr + (size_t)(b*NC + c)*16;
        const float* Km = intr + (size_t)(b*NC + c)*9;
        bool valid; int flat;
        proj_one(E, Km, x, y, z, Ws, Hs, sx, sy, valid, flat);
        sFlat[c*TILE + r] = valid ? flat : -1;
    }
    __syncthreads();

    // ---------- A2: gather-average -> sX bf16 ----------
    for (int r = w; r < TILE; r += 4) {
        const int n = base + r;
        const int b = n / NV;
        float a0x=0.f, a0y=0.f, a1x=0.f, a1y=0.f, a2x=0.f, a2y=0.f;
        int cnt = 0;
        #pragma unroll
        for (int c = 0; c < NC; ++c) {
            const int flat = sFlat[c*TILE + r];
            if (flat >= 0) {    // wave-uniform branch
                const float2* tp = (const float2*)(patch + ((size_t)(b*NC + c)*NM + flat)*ND);
                const float2 t0 = tp[lane];
                const float2 t1 = tp[lane + 64];
                const float2 t2 = tp[lane + 128];
                a0x += t0.x; a0y += t0.y;
                a1x += t1.x; a1y += t1.y;
                a2x += t2.x; a2y += t2.y;
                ++cnt;
            }
        }
        const float inv = 1.0f / fmaxf((float)cnt, 1.0f);
        unsigned* dst = (unsigned*)sX + r*228 + 32;   // img dims start at ushort 64
        dst[lane]       = pack2bf(a0x*inv, a0y*inv);  // dims 2*lane,   +1
        dst[64 + lane]  = pack2bf(a1x*inv, a1y*inv);  // dims 128+2*lane
        dst[128 + lane] = pack2bf(a2x*inv, a2y*inv);  // dims 256+2*lane
        sX[r*456 + lane] = f2bf(vfeat[(size_t)n*NF + lane]);
    }
    __syncthreads();

    // ---------- GEMM1 (MFMA): h1 = relu(X(32x448) @ W1(448x256) + b1) ----------
    const bf8_t* w1p = (const bf8_t*)w1p_;
    const f4_t zero = {0.f, 0.f, 0.f, 0.f};
    f4_t acc1[2][4];
    #pragma unroll
    for (int a = 0; a < 2; ++a)
        #pragma unroll
        for (int q = 0; q < 4; ++q) acc1[a][q] = zero;

    for (int kc = 0; kc < 14; ++kc) {
        const bf8_t a0 = *(const bf8_t*)&sX[ mrow      *456 + kc*32 + kg*8];
        const bf8_t a1 = *(const bf8_t*)&sX[(mrow + 16)*456 + kc*32 + kg*8];
        const bf8_t* bp = w1p + (size_t)((kc*16 + w*4)*64 + lane);
        #pragma unroll
        for (int nf = 0; nf < 4; ++nf) {
            const bf8_t bfr = bp[nf*64];
            acc1[0][nf] = __builtin_amdgcn_mfma_f32_16x16x32_bf16(a0, bfr, acc1[0][nf], 0, 0, 0);
            acc1[1][nf] = __builtin_amdgcn_mfma_f32_16x16x32_bf16(a1, bfr, acc1[1][nf], 0, 0, 0);
        }
    }
    #pragma unroll
    for (int nf = 0; nf < 4; ++nf) {
        const float bb = b1[w*64 + nf*16 + mrow];
        #pragma unroll
        for (int mf = 0; mf < 2; ++mf)
            #pragma unroll
            for (int r = 0; r < 4; ++r) {
                const float v = fmaxf(acc1[mf][nf][r] + bb, 0.f);
                sH1[(mf*16 + kg*4 + r)*264 + w*64 + nf*16 + mrow] = f2bf(v);
            }
    }
    __syncthreads();

    // stage W3 + b3 into overlay region (sX dead)
    *(f4_t*)&sW3[tid*4] = *(const f4_t*)&W3[tid*4];
    if (tid < 16) sB3[tid] = b3[tid];

    // ---------- GEMM2 (MFMA): h2 = relu(h1(32x256) @ W2(256x64) + b2) ----------
    const bf8_t* w2p = (const bf8_t*)w2p_;
    f4_t acc2[2];
    acc2[0] = zero; acc2[1] = zero;
    for (int kc = 0; kc < 8; ++kc) {
        const bf8_t a0 = *(const bf8_t*)&sH1[ mrow      *264 + kc*32 + kg*8];
        const bf8_t a1 = *(const bf8_t*)&sH1[(mrow + 16)*264 + kc*32 + kg*8];
        const bf8_t bfr = w2p[(kc*4 + w)*64 + lane];
        acc2[0] = __builtin_amdgcn_mfma_f32_16x16x32_bf16(a0, bfr, acc2[0], 0, 0, 0);
        acc2[1] = __builtin_amdgcn_mfma_f32_16x16x32_bf16(a1, bfr, acc2[1], 0, 0, 0);
    }
    {   // h2 f32 [n2][m] (pad 36)
        const float bb = b2[w*16 + mrow];
        #pragma unroll
        for (int mf = 0; mf < 2; ++mf) {
            f4_t v;
            #pragma unroll
            for (int r = 0; r < 4; ++r) v[r] = fmaxf(acc2[mf][r] + bb, 0.f);
            *(f4_t*)&sH2[(w*16 + mrow)*36 + mf*16 + kg*4] = v;
        }
    }
    __syncthreads();

    // ---------- GEMM3 (VALU fp32): scores = h2(32x64) @ W3(64x16) + b3 ----------
    const int m3 = tid >> 3;            // voxel 0..31
    const int cp = (tid & 7) << 1;      // col pair
    float s0 = sB3[cp], s1 = sB3[cp+1];
    #pragma unroll 8
    for (int k = 0; k < 64; ++k) {
        const float a  = sH2[k*36 + m3];
        const float2 wv = *(const float2*)&sW3[k*16 + cp];
        s0 += a*wv.x;
        s1 += a*wv.y;
    }
    *(float2*)&scores[(size_t)(base + m3)*16 + cp] = make_float2(s0, s1);
}

// out[b,p,:] = scores[b*V + idx[b,p], :]
__global__ __launch_bounds__(256) void gather_kernel(
    const float* __restrict__ scores,
    const int* __restrict__ p2v,
    float* __restrict__ out)
{
    const int g  = blockIdx.x * 256 + threadIdx.x;  // < 800000
    const int q  = g & 3;
    const int pl = g >> 2;
    const int b  = pl / NP;
    const int idx = p2v[pl];
    const float4 val = *(const float4*)&scores[((size_t)(b*NV + idx))*16 + q*4];
    *(float4*)&out[(size_t)g*4] = val;
}

extern "C" void kernel_launch(void* const* d_in, const int* in_sizes, int n_in,
                              void* d_out, int out_size, void* d_ws, size_t ws_size,
                              hipStream_t stream) {
    const float* patch = (const float*)d_in[0];
    const float* vfeat = (const float*)d_in[1];
    const float* vcoord= (const float*)d_in[2];
    const float* imsz  = (const float*)d_in[3];
    const float* intr  = (const float*)d_in[4];
    const float* extr  = (const float*)d_in[5];
    const int*   p2v   = (const int*)d_in[6];
    const float* W1 = (const float*)d_in[7];
    const float* b1 = (const float*)d_in[8];
    const float* W2 = (const float*)d_in[9];
    const float* b2 = (const float*)d_in[10];
    const float* W3 = (const float*)d_in[11];
    const float* b3 = (const float*)d_in[12];

    float* scores = (float*)d_ws;                                       // 6,400,000 B
    unsigned short* w1pack = (unsigned short*)((char*)d_ws + 6400000);  // 229,376 B
    unsigned short* w2pack = (unsigned short*)((char*)d_ws + 6400000 + 229376); // 32,768 B

    pack_w1<<<448, 256, 0, stream>>>(W1, w1pack);
    pack_w2<<<64, 256, 0, stream>>>(W2, w2pack);
    fuse_mlp_kernel<<<NROW/TILE, 256, 0, stream>>>(
        patch, vfeat, vcoord, imsz, intr, extr,
        b1, b2, W3, b3, w1pack, w2pack, scores);
    gather_kernel<<<(NB*NP*4)/256, 256, 0, stream>>>(scores, p2v, (float*)d_out);
}

// Round 11
// 68.532 us; speedup vs baseline: 7.4486x; 1.7081x over previous
//
#include <hip/hip_runtime.h>

#define NB 2
#define NC 6
#define NV 50000
#define ND 384
#define NF 64
#define NP 100000
#define NM 1369
#define NROW (NB*NV)   // 100000
#define TILE 32        // voxels per block -> 3125 blocks

typedef __attribute__((ext_vector_type(8))) short bf8_t;   // 8 bf16 (4 VGPRs)
typedef __attribute__((ext_vector_type(4))) float f4_t;    // 4 fp32 acc

// RNE float->bf16 (inputs finite)
__device__ inline unsigned short f2bf(float x) {
    unsigned u = __builtin_bit_cast(unsigned, x);
    u += 0x7fffu + ((u >> 16) & 1u);
    return (unsigned short)(u >> 16);
}
__device__ inline unsigned pack2bf(float lo, float hi) {
    return (unsigned)f2bf(lo) | ((unsigned)f2bf(hi) << 16);
}

// fp32 projection matching numpy einsum exactly (verified r8-r10: passes)
__device__ inline void proj_one(const float* __restrict__ E,
                                const float* __restrict__ Km,
                                float x, float y, float z,
                                float Ws, float Hs, float sx, float sy,
                                bool& valid, int& flat)
{
#pragma clang fp contract(off)
    const float X = ((E[0]*x + E[1]*y) + E[2]*z) + E[3];
    const float Y = ((E[4]*x + E[5]*y) + E[6]*z) + E[7];
    const float Z = ((E[8]*x + E[9]*y) + E[10]*z) + E[11];
    const float p0 = (Km[0]*X + Km[1]*Y) + Km[2]*Z;
    const float p1 = (Km[3]*X + Km[4]*Y) + Km[5]*Z;
    const float p2 = (Km[6]*X + Km[7]*Y) + Km[8]*Z;
    const float den = fmaxf(p2, 1e-12f);
    const float u = p0 / den;
    const float v = p1 / den;
    valid = (Z > 0.0f) & (u >= 0.0f) & (u < Ws) & (v >= 0.0f) & (v < Hs);
    const float us = u * sx;
    const float vs = v * sy;
    int px = (int)(us / 14.0f);
    int py = (int)(vs / 14.0f);
    px = px < 0 ? 0 : (px > 36 ? 36 : px);
    py = py < 0 ? 0 : (py > 36 ? 36 : py);
    flat = py*37 + px;
}

// Prepack W1 (448x256 f32) -> fragment-ordered bf16 (1KB contig per wave-frag).
__global__ __launch_bounds__(256) void pack_w1(const float* __restrict__ W1,
                                               unsigned short* __restrict__ out) {
    const int t = blockIdx.x*256 + threadIdx.x;      // < 448*256
    const int k = t >> 8, n = t & 255;
    const int kc = k >> 5, g = (k >> 3) & 3, i = k & 7;
    const int w = n >> 6, nf = (n >> 4) & 3, m = n & 15;
    out[(((kc*16 + w*4 + nf)*64 + g*16 + m) << 3) + i] = f2bf(W1[k*256 + n]);
}

// Prepack W2 (256x64)
__global__ __launch_bounds__(256) void pack_w2(const float* __restrict__ W2,
                                               unsigned short* __restrict__ out) {
    const int t = blockIdx.x*256 + threadIdx.x;      // < 256*64
    const int k = t >> 6, n = t & 63;
    const int kc = k >> 5, g = (k >> 3) & 3, i = k & 7;
    const int nf = n >> 4, m = n & 15;
    out[(((kc*4 + nf)*64 + g*16 + m) << 3) + i] = f2bf(W2[k*64 + n]);
}

// Prepack W3 (64x16): frag kc (k=kc*32+(l>>4)*8+i, col=l&15)
__global__ __launch_bounds__(256) void pack_w3(const float* __restrict__ W3,
                                               unsigned short* __restrict__ out) {
    const int t = blockIdx.x*256 + threadIdx.x;      // < 64*16
    const int k = t >> 4, n = t & 15;
    const int kc = k >> 5, g = (k >> 3) & 3, i = k & 7;
    out[((kc*64 + g*16 + n) << 3) + i] = f2bf(W3[k*16 + n]);
}

// Fused: A1 pair-parallel projection -> A2 gather (2-row unroll) -> MFMA MLP.
// LDS: sX 29,184B + sFlat 768B = 29,952B -> 5 blocks/CU.
// sH1 (16,896B) and sH2bf (4,608B) overlay sX after GEMM1 reads complete.
__global__ __launch_bounds__(256, 5) void fuse_mlp_kernel(
    const float* __restrict__ patch,   // (B,C,M,D)
    const float* __restrict__ vfeat,   // (B,V,F)
    const float* __restrict__ vcoord,  // (B,V,3)
    const float* __restrict__ imsz,    // (B,2)
    const float* __restrict__ intr,    // (B,C,3,3)
    const float* __restrict__ extr,    // (B,C,4,4)
    const float* __restrict__ b1,
    const float* __restrict__ b2,
    const float* __restrict__ b3,
    const unsigned short* __restrict__ w1p_,  // packed bf16 W1
    const unsigned short* __restrict__ w2p_,  // packed bf16 W2
    const unsigned short* __restrict__ w3p_,  // packed bf16 W3
    float* __restrict__ scores)        // ws: (B*V,16)
{
    __shared__ __align__(16) unsigned short sX[TILE*456];   // X bf16 [m][k]
    __shared__ int sFlat[NC*TILE];                          // [cam][voxel]: flat or -1
    unsigned short* sH1   = sX;          // overlay: h1 bf16 [32][264] (16,896B)
    unsigned short* sH2bf = sX + 8448;   // overlay: h2 bf16 [32][72]  (4,608B)

    const int tid  = threadIdx.x;
    const int base = blockIdx.x * TILE;
    const int lane = tid & 63;
    const int w    = tid >> 6;         // wave 0..3
    const int mrow = lane & 15;
    const int kg   = lane >> 4;

    // ---------- prefetch vfeat for this wave's 8 rows (issue at entry) ----------
    float vf[8];
    #pragma unroll
    for (int i = 0; i < 8; ++i)
        vf[i] = vfeat[(size_t)(base + w + 4*i)*NF + lane];

    // ---------- A1: pair-parallel projection (one thread = one voxel-cam) ----------
    if (tid < NC*TILE) {
        const int r = tid & 31, c = tid >> 5;
        const int n = base + r;
        const int b = n / NV;
        const float x = vcoord[(size_t)n*3+0];
        const float y = vcoord[(size_t)n*3+1];
        const float z = vcoord[(size_t)n*3+2];
        const float Hs = imsz[b*2+0];
        const float Ws = imsz[b*2+1];
        const float sx = 518.0f / fmaxf(Ws, 1e-6f);
        const float sy = 518.0f / fmaxf(Hs, 1e-6f);
        const float* E  = extr + (size_t)(b*NC + c)*16;
        const float* Km = intr + (size_t)(b*NC + c)*9;
        bool valid; int flat;
        proj_one(E, Km, x, y, z, Ws, Hs, sx, sy, valid, flat);
        sFlat[c*TILE + r] = valid ? flat : -1;
    }
    __syncthreads();

    // ---------- A2: gather-average, two rows in flight ----------
    #pragma unroll
    for (int t = 0; t < 4; ++t) {
        const int r0 = w + 8*t, r1 = r0 + 4;
        const int n0 = base + r0, n1 = base + r1;
        const int b0 = n0 / NV, b1b = n1 / NV;
        float A0x=0.f,A0y=0.f,A1x=0.f,A1y=0.f,A2x=0.f,A2y=0.f; int cnt0 = 0;
        float B0x=0.f,B0y=0.f,B1x=0.f,B1y=0.f,B2x=0.f,B2y=0.f; int cnt1 = 0;
        #pragma unroll
        for (int c = 0; c < NC; ++c) {
            const int f0 = sFlat[c*TILE + r0];
            const int f1 = sFlat[c*TILE + r1];
            if (f0 >= 0) {
                const float2* tp = (const float2*)(patch + ((size_t)(b0*NC + c)*NM + f0)*ND);
                const float2 t0 = tp[lane];
                const float2 t1 = tp[lane + 64];
                const float2 t2 = tp[lane + 128];
                A0x += t0.x; A0y += t0.y;
                A1x += t1.x; A1y += t1.y;
                A2x += t2.x; A2y += t2.y;
                ++cnt0;
            }
            if (f1 >= 0) {
                const float2* tp = (const float2*)(patch + ((size_t)(b1b*NC + c)*NM + f1)*ND);
                const float2 t0 = tp[lane];
                const float2 t1 = tp[lane + 64];
                const float2 t2 = tp[lane + 128];
                B0x += t0.x; B0y += t0.y;
                B1x += t1.x; B1y += t1.y;
                B2x += t2.x; B2y += t2.y;
                ++cnt1;
            }
        }
        const float inv0 = 1.0f / fmaxf((float)cnt0, 1.0f);
        const float inv1 = 1.0f / fmaxf((float)cnt1, 1.0f);
        unsigned* d0 = (unsigned*)sX + r0*228 + 32;
        d0[lane]       = pack2bf(A0x*inv0, A0y*inv0);
        d0[64 + lane]  = pack2bf(A1x*inv0, A1y*inv0);
        d0[128 + lane] = pack2bf(A2x*inv0, A2y*inv0);
        sX[r0*456 + lane] = f2bf(vf[2*t]);
        unsigned* d1 = (unsigned*)sX + r1*228 + 32;
        d1[lane]       = pack2bf(B0x*inv1, B0y*inv1);
        d1[64 + lane]  = pack2bf(B1x*inv1, B1y*inv1);
        d1[128 + lane] = pack2bf(B2x*inv1, B2y*inv1);
        sX[r1*456 + lane] = f2bf(vf[2*t + 1]);
    }
    __syncthreads();

    // ---------- GEMM1 (MFMA): h1 = relu(X(32x448) @ W1(448x256) + b1) ----------
    const bf8_t* w1p = (const bf8_t*)w1p_;
    const f4_t zero = {0.f, 0.f, 0.f, 0.f};
    f4_t acc1[2][4];
    #pragma unroll
    for (int a = 0; a < 2; ++a)
        #pragma unroll
        for (int q = 0; q < 4; ++q) acc1[a][q] = zero;

    for (int kc = 0; kc < 14; ++kc) {
        const bf8_t a0 = *(const bf8_t*)&sX[ mrow      *456 + kc*32 + kg*8];
        const bf8_t a1 = *(const bf8_t*)&sX[(mrow + 16)*456 + kc*32 + kg*8];
        const bf8_t* bp = w1p + (size_t)((kc*16 + w*4)*64 + lane);
        #pragma unroll
        for (int nf = 0; nf < 4; ++nf) {
            const bf8_t bfr = bp[nf*64];
            acc1[0][nf] = __builtin_amdgcn_mfma_f32_16x16x32_bf16(a0, bfr, acc1[0][nf], 0, 0, 0);
            acc1[1][nf] = __builtin_amdgcn_mfma_f32_16x16x32_bf16(a1, bfr, acc1[1][nf], 0, 0, 0);
        }
    }
    __syncthreads();   // all sX reads complete -> safe to overlay

    // bias+relu -> sH1 bf16 [m][k2] (overlay)
    #pragma unroll
    for (int nf = 0; nf < 4; ++nf) {
        const float bb = b1[w*64 + nf*16 + mrow];
        #pragma unroll
        for (int mf = 0; mf < 2; ++mf)
            #pragma unroll
            for (int r = 0; r < 4; ++r) {
                const float v = fmaxf(acc1[mf][nf][r] + bb, 0.f);
                sH1[(mf*16 + kg*4 + r)*264 + w*64 + nf*16 + mrow] = f2bf(v);
            }
    }
    __syncthreads();

    // ---------- GEMM2 (MFMA): h2 = relu(h1(32x256) @ W2(256x64) + b2) ----------
    const bf8_t* w2p = (const bf8_t*)w2p_;
    f4_t acc2[2];
    acc2[0] = zero; acc2[1] = zero;
    for (int kc = 0; kc < 8; ++kc) {
        const bf8_t a0 = *(const bf8_t*)&sH1[ mrow      *264 + kc*32 + kg*8];
        const bf8_t a1 = *(const bf8_t*)&sH1[(mrow + 16)*264 + kc*32 + kg*8];
        const bf8_t bfr = w2p[(kc*4 + w)*64 + lane];
        acc2[0] = __builtin_amdgcn_mfma_f32_16x16x32_bf16(a0, bfr, acc2[0], 0, 0, 0);
        acc2[1] = __builtin_amdgcn_mfma_f32_16x16x32_bf16(a1, bfr, acc2[1], 0, 0, 0);
    }
    {   // h2 -> sH2bf bf16 [m][72] (region disjoint from sH1)
        const float bb = b2[w*16 + mrow];
        #pragma unroll
        for (int mf = 0; mf < 2; ++mf)
            #pragma unroll
            for (int r = 0; r < 4; ++r) {
                const float v = fmaxf(acc2[mf][r] + bb, 0.f);
                sH2bf[(mf*16 + kg*4 + r)*72 + w*16 + mrow] = f2bf(v);
            }
    }
    __syncthreads();

    // ---------- GEMM3 (MFMA, waves 0-1): scores = h2(32x64) @ W3(64x16) + b3 ----------
    if (w < 2) {
        const bf8_t* w3p = (const bf8_t*)w3p_;
        f4_t acc3 = zero;
        #pragma unroll
        for (int kc = 0; kc < 2; ++kc) {
            const bf8_t a = *(const bf8_t*)&sH2bf[(w*16 + mrow)*72 + kc*32 + kg*8];
            const bf8_t bfr = w3p[kc*64 + lane];
            acc3 = __builtin_amdgcn_mfma_f32_16x16x32_bf16(a, bfr, acc3, 0, 0, 0);
        }
        const float bb = b3[mrow];
        #pragma unroll
        for (int r = 0; r < 4; ++r)
            scores[(size_t)(base + w*16 + kg*4 + r)*16 + mrow] = acc3[r] + bb;
    }
}

// out[b,p,:] = scores[b*V + idx[b,p], :]
__global__ __launch_bounds__(256) void gather_kernel(
    const float* __restrict__ scores,
    const int* __restrict__ p2v,
    float* __restrict__ out)
{
    const int g  = blockIdx.x * 256 + threadIdx.x;  // < 800000
    const int q  = g & 3;
    const int pl = g >> 2;
    const int b  = pl / NP;
    const int idx = p2v[pl];
    const float4 val = *(const float4*)&scores[((size_t)(b*NV + idx))*16 + q*4];
    *(float4*)&out[(size_t)g*4] = val;
}

extern "C" void kernel_launch(void* const* d_in, const int* in_sizes, int n_in,
                              void* d_out, int out_size, void* d_ws, size_t ws_size,
                              hipStream_t stream) {
    const float* patch = (const float*)d_in[0];
    const float* vfeat = (const float*)d_in[1];
    const float* vcoord= (const float*)d_in[2];
    const float* imsz  = (const float*)d_in[3];
    const float* intr  = (const float*)d_in[4];
    const float* extr  = (const float*)d_in[5];
    const int*   p2v   = (const int*)d_in[6];
    const float* W1 = (const float*)d_in[7];
    const float* b1 = (const float*)d_in[8];
    const float* W2 = (const float*)d_in[9];
    const float* b2 = (const float*)d_in[10];
    const float* W3 = (const float*)d_in[11];
    const float* b3 = (const float*)d_in[12];

    float* scores = (float*)d_ws;                                       // 6,400,000 B
    unsigned short* w1pack = (unsigned short*)((char*)d_ws + 6400000);  // 229,376 B
    unsigned short* w2pack = (unsigned short*)((char*)d_ws + 6629376);  // 32,768 B
    unsigned short* w3pack = (unsigned short*)((char*)d_ws + 6662144);  // 2,048 B

    pack_w1<<<448, 256, 0, stream>>>(W1, w1pack);
    pack_w2<<<64, 256, 0, stream>>>(W2, w2pack);
    pack_w3<<<4, 256, 0, stream>>>(W3, w3pack);
    fuse_mlp_kernel<<<NROW/TILE, 256, 0, stream>>>(
        patch, vfeat, vcoord, imsz, intr, extr,
        b1, b2, b3, w1pack, w2pack, w3pack, scores);
    gather_kernel<<<(NB*NP*4)/256, 256, 0, stream>>>(scores, p2v, (float*)d_out);
}